// Round 5
// baseline (239.750 us; speedup 1.0000x reference)
//
#include <hip/hip_runtime.h>
#include <hip/hip_bf16.h>
#include <stdint.h>

#define B_ROWS 2048
#define SEQ 512
#define VOC 30000
#define DMODEL 768
#define K1 1.2f
#define BPAR 0.75f
#define NT 192   // 2 token-groups x 96 threads; each thread owns 8 bf16 dims (16 B)
#define GSZ 96
#define PF 8     // prefetch depth (outstanding 16B loads per thread)

// ---------------- Kernel 1: transpose W [768][30000] f32 -> Wb [30000][768] bf16 -------
__global__ void transpose_W(const float* __restrict__ W, __hip_bfloat16* __restrict__ Wb) {
    __shared__ float tile[32][33];
    int tBase = blockIdx.x * 32;   // vocab dim
    int jBase = blockIdx.y * 32;   // 768 dim
    int tx = threadIdx.x, ty = threadIdx.y;  // block (32,8)
#pragma unroll
    for (int k = 0; k < 4; k++) {
        int j = jBase + ty + k * 8;
        int t = tBase + tx;
        float v = (t < VOC) ? W[(size_t)j * VOC + t] : 0.f;
        tile[ty + k * 8][tx] = v;
    }
    __syncthreads();
#pragma unroll
    for (int k = 0; k < 4; k++) {
        int t = tBase + ty + k * 8;
        if (t < VOC) Wb[(size_t)t * DMODEL + jBase + tx] = __float2bfloat16(tile[tx][ty + k * 8]);
    }
}

// fused bf16x8 (as uint4) * w -> 8 f32 accumulators
__device__ __forceinline__ void fma8(float* a, const uint4& r, float w) {
    a[0] = fmaf(w, __uint_as_float(r.x << 16), a[0]);
    a[1] = fmaf(w, __uint_as_float(r.x & 0xffff0000u), a[1]);
    a[2] = fmaf(w, __uint_as_float(r.y << 16), a[2]);
    a[3] = fmaf(w, __uint_as_float(r.y & 0xffff0000u), a[3]);
    a[4] = fmaf(w, __uint_as_float(r.z << 16), a[4]);
    a[5] = fmaf(w, __uint_as_float(r.z & 0xffff0000u), a[5]);
    a[6] = fmaf(w, __uint_as_float(r.w << 16), a[6]);
    a[7] = fmaf(w, __uint_as_float(r.w & 0xffff0000u), a[7]);
}

// ---------------- Kernel 2: per-row BM25 sparse accumulate + normalize ----------------
// One block per document. Tokens compacted + bitonic-sorted in LDS; tf = run length.
// Two 96-thread groups process alternating sorted positions with 16B row chunks;
// all blocks sweep Wb in ascending vocab order in phase -> L2 reuse.
__launch_bounds__(NT, 6)
__global__ void bm25_main(const int* __restrict__ ids, const int* __restrict__ mask,
                          const __hip_bfloat16* __restrict__ Wb,
                          float* __restrict__ out) {
    __shared__ int   stoks[SEQ];
    __shared__ uint2 tw[SEQ];        // .x = token*1536 (byte offset), .y = bitcast(weight)
    __shared__ int   nv;
    __shared__ float accred[DMODEL]; // cross-group combine
    __shared__ float ssbuf[GSZ];
    __shared__ float wred;

    int b = blockIdx.x;
    int tid = threadIdx.x;
    const char* __restrict__ Wbase = (const char*)Wb;
    int g = tid / GSZ;                        // token-group 0/1
    int lane = tid - g * GSZ;
    uint32_t col16 = (uint32_t)lane << 4;     // this thread's 16B chunk within a row

    if (tid == 0) nv = 0;
    __syncthreads();

    // compact valid tokens (order irrelevant; sort follows)
    for (int i = tid; i < SEQ; i += NT) {
        int id = ids[(size_t)b * SEQ + i];
        int m  = mask[(size_t)b * SEQ + i];
        if (m == 1 && id > 100 && id < VOC) {
            stoks[atomicAdd(&nv, 1)] = id;
        }
    }
    __syncthreads();
    int n = nv;  // == doc_len (positions with multiplicity)

    // pad to 512 with +inf keys
    for (int i = n + tid; i < SEQ; i += NT) stoks[i] = 0x7fffffff;

    // bitonic sort of 512 ints (first barrier inside loop covers padding writes)
    for (int k = 2; k <= SEQ; k <<= 1) {
        for (int j = k >> 1; j > 0; j >>= 1) {
            __syncthreads();
            for (int i = tid; i < SEQ; i += NT) {
                int ixj = i ^ j;
                if (ixj > i) {
                    int a = stoks[i], c = stoks[ixj];
                    if ((a > c) == ((i & k) == 0)) { stoks[i] = c; stoks[ixj] = a; }
                }
            }
        }
    }
    __syncthreads();

    // per-position {byte offset, weight}: w = (K1+1)/(tf + K1*len_norm), tf = run length
    float kln = K1 * fmaxf(1.0f + BPAR * ((float)n / 100.0f - 1.0f), 0.5f);
    for (int i = tid; i < n; i += NT) {
        int t = stoks[i];
        int lo = i; while (lo > 0 && stoks[lo - 1] == t) lo--;
        int hi = i; while (hi < n - 1 && stoks[hi + 1] == t) hi++;
        float w = (K1 + 1.0f) / ((float)(hi - lo + 1) + kln);
        tw[i] = make_uint2((uint32_t)t * (DMODEL * 2u), __float_as_uint(w));
    }
    __syncthreads();

    // gather-accumulate: group g handles sorted positions p = 2*i + g (ascending sweep)
    float a[8] = {0.f, 0.f, 0.f, 0.f, 0.f, 0.f, 0.f, 0.f};
    int m = (n + 1 - g) >> 1;        // tokens for this group
    int mfull = m & ~(PF - 1);
    for (int i0 = 0; i0 < mfull; i0 += PF) {
        uint4 r[PF]; float w[PF];
#pragma unroll
        for (int q = 0; q < PF; q++) {
            uint2 t_ = tw[((i0 + q) << 1) | g];
            r[q] = *(const uint4*)(Wbase + (t_.x + col16));
            w[q] = __uint_as_float(t_.y);
        }
#pragma unroll
        for (int q = 0; q < PF; q++) fma8(a, r[q], w[q]);
    }
    for (int i = mfull; i < m; i++) {
        uint2 t_ = tw[(i << 1) | g];
        uint4 r = *(const uint4*)(Wbase + (t_.x + col16));
        fma8(a, r, __uint_as_float(t_.y));
    }

    // cross-group combine (dims lane*8 .. lane*8+7)
    if (g == 1) {
        ((float4*)accred)[lane * 2]     = make_float4(a[0], a[1], a[2], a[3]);
        ((float4*)accred)[lane * 2 + 1] = make_float4(a[4], a[5], a[6], a[7]);
    }
    __syncthreads();
    if (g == 0) {
        float4 p0 = ((float4*)accred)[lane * 2];
        float4 p1 = ((float4*)accred)[lane * 2 + 1];
        a[0] += p0.x; a[1] += p0.y; a[2] += p0.z; a[3] += p0.w;
        a[4] += p1.x; a[5] += p1.y; a[6] += p1.z; a[7] += p1.w;
        float ss = 0.f;
#pragma unroll
        for (int d = 0; d < 8; d++) ss = fmaf(a[d], a[d], ss);
        ssbuf[lane] = ss;
    }
    __syncthreads();
    if (tid < 64) {
        float s = ssbuf[tid] + (tid < 32 ? ssbuf[tid + 64] : 0.f);
#pragma unroll
        for (int off = 32; off > 0; off >>= 1) s += __shfl_down(s, off);
        if (tid == 0) wred = s;
    }
    __syncthreads();

    if (g == 0) {
        float inv = rsqrtf(fmaxf(wred, 1e-30f));
        float4* outp = (float4*)(out + (size_t)b * DMODEL + lane * 8);
        outp[0] = make_float4(a[0] * inv, a[1] * inv, a[2] * inv, a[3] * inv);
        outp[1] = make_float4(a[4] * inv, a[5] * inv, a[6] * inv, a[7] * inv);
    }
}

extern "C" void kernel_launch(void* const* d_in, const int* in_sizes, int n_in,
                              void* d_out, int out_size, void* d_ws, size_t ws_size,
                              hipStream_t stream) {
    const int*   ids  = (const int*)d_in[0];
    const int*   mask = (const int*)d_in[1];
    const float* W    = (const float*)d_in[2];
    float* out = (float*)d_out;

    __hip_bfloat16* Wb = (__hip_bfloat16*)d_ws;            // 30000*768*2 = 46,080,000 B

    dim3 tgrid((VOC + 31) / 32, DMODEL / 32);
    dim3 tblock(32, 8);
    transpose_W<<<tgrid, tblock, 0, stream>>>(W, Wb);

    bm25_main<<<B_ROWS, NT, 0, stream>>>(ids, mask, Wb, out);
}

// Round 6
// 205.471 us; speedup vs baseline: 1.1668x; 1.1668x over previous
//
#include <hip/hip_runtime.h>
#include <hip/hip_bf16.h>
#include <stdint.h>

#define B_ROWS 2048
#define SEQ 512
#define VOC 30000
#define DMODEL 768
#define K1 1.2f
#define BPAR 0.75f
#define NT 192   // 3 waves; each thread owns one ushort4 (4 bf16) chunk of 768 dims
#define PF 8     // prefetch depth (outstanding global loads per thread)

// ---------------- Kernel 1: transpose W [768][30000] f32 -> Wb [30000][768] bf16 -------
__global__ void transpose_W(const float* __restrict__ W, __hip_bfloat16* __restrict__ Wb) {
    __shared__ float tile[32][33];
    int tBase = blockIdx.x * 32;   // vocab dim
    int jBase = blockIdx.y * 32;   // 768 dim
    int tx = threadIdx.x, ty = threadIdx.y;  // block (32,8)
#pragma unroll
    for (int k = 0; k < 4; k++) {
        int j = jBase + ty + k * 8;
        int t = tBase + tx;
        float v = (t < VOC) ? W[(size_t)j * VOC + t] : 0.f;
        tile[ty + k * 8][tx] = v;
    }
    __syncthreads();
#pragma unroll
    for (int k = 0; k < 4; k++) {
        int t = tBase + ty + k * 8;
        if (t < VOC) Wb[(size_t)t * DMODEL + jBase + tx] = __float2bfloat16(tile[tx][ty + k * 8]);
    }
}

__device__ __forceinline__ float b2f(unsigned short h) {
    union { uint32_t u; float f; } v; v.u = ((uint32_t)h) << 16; return v.f;
}

// ---------------- Kernel 2: per-row BM25 sparse accumulate + normalize ----------------
// One block (192 threads) per document. Valid tokens compacted + bitonic-sorted in LDS;
// tf = run length. All blocks sweep Wb in ascending vocab order in phase -> the ~4.3
// uses of each row per XCD hit L2 (FETCH sits at the 8x46MB compulsory floor).
// Inner loop: R3's compiler-scheduled PF=8 batch (no cross-batch register copies) with
// per-token {byte_offset, weight} packed in LDS -> single v_add addressing.
__launch_bounds__(NT, 6)
__global__ void bm25_main(const int* __restrict__ ids, const int* __restrict__ mask,
                          const __hip_bfloat16* __restrict__ Wb,
                          float* __restrict__ out) {
    __shared__ int   stoks[SEQ];
    __shared__ uint2 tw[SEQ];     // .x = token*1536 (byte offset), .y = bitcast(weight)
    __shared__ int   nv;
    __shared__ float wred[3];

    int b = blockIdx.x;
    int tid = threadIdx.x;
    const char* __restrict__ Wbase = (const char*)Wb;   // wave-uniform SGPR base
    uint32_t tid8 = (uint32_t)tid << 3;                 // this thread's 8B chunk offset

    if (tid == 0) nv = 0;
    __syncthreads();

    // compact valid tokens (order irrelevant; sort follows)
    for (int i = tid; i < SEQ; i += NT) {
        int id = ids[(size_t)b * SEQ + i];
        int m  = mask[(size_t)b * SEQ + i];
        if (m == 1 && id > 100 && id < VOC) {
            stoks[atomicAdd(&nv, 1)] = id;
        }
    }
    __syncthreads();
    int n = nv;  // == doc_len (positions with multiplicity)

    // pad to 512 with +inf keys
    for (int i = n + tid; i < SEQ; i += NT) stoks[i] = 0x7fffffff;

    // bitonic sort of 512 ints (first barrier inside loop covers padding writes)
    for (int k = 2; k <= SEQ; k <<= 1) {
        for (int j = k >> 1; j > 0; j >>= 1) {
            __syncthreads();
            for (int i = tid; i < SEQ; i += NT) {
                int ixj = i ^ j;
                if (ixj > i) {
                    int a = stoks[i], c = stoks[ixj];
                    if ((a > c) == ((i & k) == 0)) { stoks[i] = c; stoks[ixj] = a; }
                }
            }
        }
    }
    __syncthreads();

    // per-position {byte offset, weight}: w = (K1+1)/(tf + K1*len_norm), tf = run length
    float kln = K1 * fmaxf(1.0f + BPAR * ((float)n / 100.0f - 1.0f), 0.5f);
    for (int i = tid; i < n; i += NT) {
        int t = stoks[i];
        int lo = i; while (lo > 0 && stoks[lo - 1] == t) lo--;
        int hi = i; while (hi < n - 1 && stoks[hi + 1] == t) hi++;
        float w = (K1 + 1.0f) / ((float)(hi - lo + 1) + kln);
        tw[i] = make_uint2((uint32_t)t * (DMODEL * 2u), __float_as_uint(w));
    }
    __syncthreads();

    // gather-accumulate in ascending vocab order; thread owns bf16x4 chunk `tid`
    float4 acc = make_float4(0.f, 0.f, 0.f, 0.f);
    int p = 0;
    for (; p + PF <= n; p += PF) {
        ushort4 r[PF]; float w[PF];
#pragma unroll
        for (int q = 0; q < PF; q++) {
            uint2 t_ = tw[p + q];
            r[q] = *(const ushort4*)(Wbase + (t_.x + tid8));
            w[q] = __uint_as_float(t_.y);
        }
#pragma unroll
        for (int q = 0; q < PF; q++) {
            acc.x = fmaf(w[q], b2f(r[q].x), acc.x);
            acc.y = fmaf(w[q], b2f(r[q].y), acc.y);
            acc.z = fmaf(w[q], b2f(r[q].z), acc.z);
            acc.w = fmaf(w[q], b2f(r[q].w), acc.w);
        }
    }
    for (; p < n; p++) {
        uint2 t_ = tw[p];
        float w = __uint_as_float(t_.y);
        ushort4 r = *(const ushort4*)(Wbase + (t_.x + tid8));
        acc.x = fmaf(w, b2f(r.x), acc.x);
        acc.y = fmaf(w, b2f(r.y), acc.y);
        acc.z = fmaf(w, b2f(r.z), acc.z);
        acc.w = fmaf(w, b2f(r.w), acc.w);
    }

    // L2 norm over 768 dims (intermediate normalize cancels; 1e-10 term ~1e-10 rel -> drop)
    float ss = acc.x * acc.x + acc.y * acc.y + acc.z * acc.z + acc.w * acc.w;
#pragma unroll
    for (int off = 32; off > 0; off >>= 1) ss += __shfl_down(ss, off);
    if ((tid & 63) == 0) wred[tid >> 6] = ss;
    __syncthreads();
    float inv = rsqrtf(fmaxf(wred[0] + wred[1] + wred[2], 1e-30f));

    float4 o;
    o.x = acc.x * inv; o.y = acc.y * inv; o.z = acc.z * inv; o.w = acc.w * inv;
    ((float4*)(out + (size_t)b * DMODEL))[tid] = o;
}

extern "C" void kernel_launch(void* const* d_in, const int* in_sizes, int n_in,
                              void* d_out, int out_size, void* d_ws, size_t ws_size,
                              hipStream_t stream) {
    const int*   ids  = (const int*)d_in[0];
    const int*   mask = (const int*)d_in[1];
    const float* W    = (const float*)d_in[2];
    float* out = (float*)d_out;

    __hip_bfloat16* Wb = (__hip_bfloat16*)d_ws;            // 30000*768*2 = 46,080,000 B

    dim3 tgrid((VOC + 31) / 32, DMODEL / 32);
    dim3 tblock(32, 8);
    transpose_W<<<tgrid, tblock, 0, stream>>>(W, Wb);

    bm25_main<<<B_ROWS, NT, 0, stream>>>(ids, mask, Wb, out);
}

// Round 7
// 192.214 us; speedup vs baseline: 1.2473x; 1.0690x over previous
//
#include <hip/hip_runtime.h>
#include <hip/hip_bf16.h>
#include <stdint.h>

#define B_ROWS 2048
#define SEQ 512
#define VOC 30000
#define DMODEL 768
#define K1 1.2f
#define BPAR 0.75f
#define NT 192   // 3 waves; each thread owns one ushort4 (4 bf16) chunk of 768 dims
#define PF 8     // prefetch depth (outstanding global loads per thread)

// ---------------- Kernel 1: transpose W [768][30000] f32 -> Wb [30000][768] bf16 -------
__global__ void transpose_W(const float* __restrict__ W, __hip_bfloat16* __restrict__ Wb) {
    __shared__ float tile[32][33];
    int tBase = blockIdx.x * 32;   // vocab dim
    int jBase = blockIdx.y * 32;   // 768 dim
    int tx = threadIdx.x, ty = threadIdx.y;  // block (32,8)
#pragma unroll
    for (int k = 0; k < 4; k++) {
        int j = jBase + ty + k * 8;
        int t = tBase + tx;
        float v = (t < VOC) ? W[(size_t)j * VOC + t] : 0.f;
        tile[ty + k * 8][tx] = v;
    }
    __syncthreads();
#pragma unroll
    for (int k = 0; k < 4; k++) {
        int t = tBase + ty + k * 8;
        if (t < VOC) Wb[(size_t)t * DMODEL + jBase + tx] = __float2bfloat16(tile[tx][ty + k * 8]);
    }
}

// ---------------- Kernel 2: S[j] = sum_t W[j][t] (exact f32; the 1e-10*ones@W^T term) --
__global__ void colsum_W(const float* __restrict__ W, float* __restrict__ S) {
    int j = blockIdx.x;
    const float* row = W + (size_t)j * VOC;
    float s = 0.f;
    for (int t = threadIdx.x; t < VOC; t += 256) s += row[t];
    __shared__ float red[256];
    red[threadIdx.x] = s;
    __syncthreads();
    for (int off = 128; off > 0; off >>= 1) {
        if (threadIdx.x < off) red[threadIdx.x] += red[threadIdx.x + off];
        __syncthreads();
    }
    if (threadIdx.x == 0) S[j] = red[0];
}

__device__ __forceinline__ float b2f(unsigned short h) {
    union { uint32_t u; float f; } v; v.u = ((uint32_t)h) << 16; return v.f;
}

// ---------------- Kernel 3: per-row BM25 sparse accumulate + normalize ----------------
// One block (192 threads) per document. Valid tokens compacted + bitonic-sorted in LDS;
// tf = run length. All 2048 blocks co-resident (8/CU) sweep Wb in ascending vocab order
// in phase -> reuse hits L2. bf16 rows (1.5 KB) + 8-deep prefetch pipeline.
__launch_bounds__(NT, 6)
__global__ void bm25_main(const int* __restrict__ ids, const int* __restrict__ mask,
                          const __hip_bfloat16* __restrict__ Wb, const float* __restrict__ S,
                          float* __restrict__ out) {
    __shared__ int   stoks[SEQ];
    __shared__ float wts[SEQ];
    __shared__ int   nv;
    __shared__ float wred[3];

    int b = blockIdx.x;
    int tid = threadIdx.x;

    if (tid == 0) nv = 0;
    __syncthreads();

    // compact valid tokens (order irrelevant; sort follows)
    for (int i = tid; i < SEQ; i += NT) {
        int id = ids[(size_t)b * SEQ + i];
        int m  = mask[(size_t)b * SEQ + i];
        if (m == 1 && id > 100 && id < VOC) {
            stoks[atomicAdd(&nv, 1)] = id;
        }
    }
    __syncthreads();
    int n = nv;  // == doc_len (positions with multiplicity)

    // pad to 512 with +inf keys
    for (int i = n + tid; i < SEQ; i += NT) stoks[i] = 0x7fffffff;

    // bitonic sort of 512 ints (first barrier inside loop covers padding writes)
    for (int k = 2; k <= SEQ; k <<= 1) {
        for (int j = k >> 1; j > 0; j >>= 1) {
            __syncthreads();
            for (int i = tid; i < SEQ; i += NT) {
                int ixj = i ^ j;
                if (ixj > i) {
                    int a = stoks[i], c = stoks[ixj];
                    if ((a > c) == ((i & k) == 0)) { stoks[i] = c; stoks[ixj] = a; }
                }
            }
        }
    }
    __syncthreads();

    // per-position weight: score(tf)/tf = (K1+1)/(tf + K1*len_norm); tf via sorted runs
    float kln = K1 * fmaxf(1.0f + BPAR * ((float)n / 100.0f - 1.0f), 0.5f);
    for (int i = tid; i < n; i += NT) {
        int t = stoks[i];
        int lo = i; while (lo > 0 && stoks[lo - 1] == t) lo--;
        int hi = i; while (hi < n - 1 && stoks[hi + 1] == t) hi++;
        wts[i] = (K1 + 1.0f) / ((float)(hi - lo + 1) + kln);
    }
    __syncthreads();

    // gather-accumulate in ascending vocab order; thread owns bf16x4 chunk `tid`
    const ushort4* __restrict__ Wb4 = (const ushort4*)Wb;   // row stride DMODEL/4 = 192
    float4 acc = make_float4(0.f, 0.f, 0.f, 0.f);
    int p = 0;
    for (; p + PF <= n; p += PF) {
        ushort4 r[PF];
        float   w[PF];
#pragma unroll
        for (int q = 0; q < PF; q++) {
            r[q] = Wb4[(size_t)stoks[p + q] * (DMODEL / 4) + tid];
            w[q] = wts[p + q];
        }
#pragma unroll
        for (int q = 0; q < PF; q++) {
            acc.x = fmaf(w[q], b2f(r[q].x), acc.x);
            acc.y = fmaf(w[q], b2f(r[q].y), acc.y);
            acc.z = fmaf(w[q], b2f(r[q].z), acc.z);
            acc.w = fmaf(w[q], b2f(r[q].w), acc.w);
        }
    }
    for (; p < n; p++) {
        float w = wts[p];
        ushort4 r = Wb4[(size_t)stoks[p] * (DMODEL / 4) + tid];
        acc.x = fmaf(w, b2f(r.x), acc.x);
        acc.y = fmaf(w, b2f(r.y), acc.y);
        acc.z = fmaf(w, b2f(r.z), acc.z);
        acc.w = fmaf(w, b2f(r.w), acc.w);
    }

    // exact 1e-10 * ones @ W^T term (f32; also guarantees nonzero norm when n == 0)
    float4 s4 = ((const float4*)S)[tid];
    acc.x += 1e-10f * s4.x;
    acc.y += 1e-10f * s4.y;
    acc.z += 1e-10f * s4.z;
    acc.w += 1e-10f * s4.w;

    // L2 norm over 768 dims (intermediate normalize cancels algebraically)
    float ss = acc.x * acc.x + acc.y * acc.y + acc.z * acc.z + acc.w * acc.w;
#pragma unroll
    for (int off = 32; off > 0; off >>= 1) ss += __shfl_down(ss, off);
    if ((tid & 63) == 0) wred[tid >> 6] = ss;
    __syncthreads();
    float inv = 1.0f / sqrtf(wred[0] + wred[1] + wred[2]);

    float4 o;
    o.x = acc.x * inv; o.y = acc.y * inv; o.z = acc.z * inv; o.w = acc.w * inv;
    ((float4*)(out + (size_t)b * DMODEL))[tid] = o;
}

extern "C" void kernel_launch(void* const* d_in, const int* in_sizes, int n_in,
                              void* d_out, int out_size, void* d_ws, size_t ws_size,
                              hipStream_t stream) {
    const int*   ids  = (const int*)d_in[0];
    const int*   mask = (const int*)d_in[1];
    const float* W    = (const float*)d_in[2];
    float* out = (float*)d_out;

    __hip_bfloat16* Wb = (__hip_bfloat16*)d_ws;            // 30000*768*2 = 46,080,000 B
    float* S = (float*)((char*)d_ws + (size_t)VOC * DMODEL * sizeof(__hip_bfloat16));

    dim3 tgrid((VOC + 31) / 32, DMODEL / 32);
    dim3 tblock(32, 8);
    transpose_W<<<tgrid, tblock, 0, stream>>>(W, Wb);

    colsum_W<<<DMODEL, 256, 0, stream>>>(W, S);

    bm25_main<<<B_ROWS, NT, 0, stream>>>(ids, mask, Wb, S, out);
}